// Round 1
// baseline (89.047 us; speedup 1.0000x reference)
//
#include <hip/hip_runtime.h>
#include <hip/hip_bf16.h>
#include <math.h>

// Problem constants (fixed by setup_inputs in the reference)
#define N_SYS   64
#define N_ELEC  64
#define NTOT    (N_SYS * N_ELEC)   // 4096
#define DIM     256
#define HEADS   8
#define HDIM    (DIM / HEADS)      // 32
#define LN_EPS  1e-6f

// ---------------------------------------------------------------------------
// Generic tiled fp32 GEMM: C[M,N] = A[M,K] @ B[K,N]  (+ epilogue)
// EPI 0: plain            C = A@B
// EPI 1: residual         C = res + A@B
// EPI 2: mlp              C = res + silu(A@B + bias)
// 64x64 tile, BK=16, 256 threads, 4x4 outputs/thread.
// ---------------------------------------------------------------------------
template <int EPI>
__global__ __launch_bounds__(256) void gemm_k(
    const float* __restrict__ A, const float* __restrict__ B,
    const float* __restrict__ res, const float* __restrict__ bias,
    float* __restrict__ C, int M, int N, int K)
{
    __shared__ float As[16][64];      // As[k][m]
    __shared__ float Bs[16][68];      // Bs[k][n] (+4 pad, keeps 16B align)

    const int tid = threadIdx.x;
    const int bm = blockIdx.y * 64;
    const int bn = blockIdx.x * 64;
    const int tm = (tid >> 4) * 4;    // 0..60
    const int tn = (tid & 15) * 4;    // 0..60

    const int arow = tid >> 2;        // 0..63
    const int acol = (tid & 3) * 4;   // 0,4,8,12
    const int brow = tid >> 4;        // 0..15
    const int bcol = (tid & 15) * 4;  // 0..60

    float c[4][4] = {};

    for (int k0 = 0; k0 < K; k0 += 16) {
        float4 av = *(const float4*)&A[(size_t)(bm + arow) * K + k0 + acol];
        float4 bv = *(const float4*)&B[(size_t)(k0 + brow) * N + bn + bcol];
        __syncthreads();              // protect prior-iter LDS reads
        As[acol + 0][arow] = av.x;
        As[acol + 1][arow] = av.y;
        As[acol + 2][arow] = av.z;
        As[acol + 3][arow] = av.w;
        *(float4*)&Bs[brow][bcol] = bv;
        __syncthreads();
#pragma unroll
        for (int kk = 0; kk < 16; ++kk) {
            float4 a = *(const float4*)&As[kk][tm];
            float4 b = *(const float4*)&Bs[kk][tn];
            c[0][0] += a.x * b.x; c[0][1] += a.x * b.y; c[0][2] += a.x * b.z; c[0][3] += a.x * b.w;
            c[1][0] += a.y * b.x; c[1][1] += a.y * b.y; c[1][2] += a.y * b.z; c[1][3] += a.y * b.w;
            c[2][0] += a.z * b.x; c[2][1] += a.z * b.y; c[2][2] += a.z * b.z; c[2][3] += a.z * b.w;
            c[3][0] += a.w * b.x; c[3][1] += a.w * b.y; c[3][2] += a.w * b.z; c[3][3] += a.w * b.w;
        }
    }

#pragma unroll
    for (int i = 0; i < 4; ++i) {
        const int row = bm + tm + i;
#pragma unroll
        for (int j = 0; j < 4; ++j) {
            const int col = bn + tn + j;
            float v = c[i][j];
            if constexpr (EPI == 1) {
                v += res[(size_t)row * N + col];
            } else if constexpr (EPI == 2) {
                v += bias[col];
                float sg = 1.0f / (1.0f + __expf(-v));
                v = res[(size_t)row * N + col] + v * sg;
            }
            C[(size_t)row * N + col] = v;
        }
    }
}

// ---------------------------------------------------------------------------
// Attention: one block per (system, head). 256 threads (4 waves).
// S[i][j] = Q[i].K[j]/sqrt(32); softmax over i per column (j,h);
// out[i][d] = sum_j A[i][j] * V[j][d]
// ---------------------------------------------------------------------------
__global__ __launch_bounds__(256) void attn_k(
    const float* __restrict__ qkv, float* __restrict__ attn)
{
    const int s = blockIdx.x >> 3;
    const int h = blockIdx.x & 7;

    __shared__ float Ks[64][36];
    __shared__ float Vs[64][36];
    __shared__ float S[64][65];
    __shared__ float red[8][64];

    const int tid = threadIdx.x;
    const int lane = tid & 63;
    const int w = tid >> 6;

    const float* base = qkv + (size_t)s * N_ELEC * (3 * DIM);

    // stage K and V tiles (64 x 32 each)
    for (int idx = tid; idx < 64 * 8; idx += 256) {
        const int r = idx >> 3;
        const int d4 = (idx & 7) * 4;
        float4 kv = *(const float4*)&base[(size_t)r * 768 + DIM + h * HDIM + d4];
        float4 vv = *(const float4*)&base[(size_t)r * 768 + 2 * DIM + h * HDIM + d4];
        *(float4*)&Ks[r][d4] = kv;
        *(float4*)&Vs[r][d4] = vv;
    }

    // Q row (i = lane) into registers
    const int i = lane;
    float q[32];
#pragma unroll
    for (int d4 = 0; d4 < 32; d4 += 4) {
        float4 qv = *(const float4*)&base[(size_t)i * 768 + h * HDIM + d4];
        q[d4 + 0] = qv.x; q[d4 + 1] = qv.y; q[d4 + 2] = qv.z; q[d4 + 3] = qv.w;
    }
    __syncthreads();

    const float scale = 0.17677669529663687f;  // 1/sqrt(32)

    // scores: wave w computes columns j = w*16 .. w*16+15 for all rows i=lane
#pragma unroll
    for (int jj = 0; jj < 16; ++jj) {
        const int j = w * 16 + jj;
        float acc = 0.0f;
#pragma unroll
        for (int d = 0; d < 32; d += 4) {
            float4 kv = *(const float4*)&Ks[j][d];
            acc += q[d] * kv.x + q[d + 1] * kv.y + q[d + 2] * kv.z + q[d + 3] * kv.w;
        }
        S[i][j] = acc * scale;
    }
    __syncthreads();

    // column softmax (over i) — thread (w, lane): column j=lane, rows [w*16, w*16+16)
    {
        const int j = lane;
        const int r0 = w * 16;
        float m = -INFINITY;
#pragma unroll
        for (int r = 0; r < 16; ++r) m = fmaxf(m, S[r0 + r][j]);
        red[w][j] = m;
        __syncthreads();
        const float fm = fmaxf(fmaxf(red[0][j], red[1][j]), fmaxf(red[2][j], red[3][j]));
        float sum = 0.0f;
#pragma unroll
        for (int r = 0; r < 16; ++r) {
            float e = __expf(S[r0 + r][j] - fm);
            S[r0 + r][j] = e;
            sum += e;
        }
        red[4 + w][j] = sum;
        __syncthreads();
        const float inv = 1.0f / (red[4][j] + red[5][j] + red[6][j] + red[7][j]);
#pragma unroll
        for (int r = 0; r < 16; ++r) S[r0 + r][j] *= inv;
    }
    __syncthreads();

    // PV: thread handles d = tid&31, rows i0..i0+7
    {
        const int d = tid & 31;
        const int i0 = (tid >> 5) * 8;
        float acc[8] = {};
        for (int j = 0; j < 64; ++j) {
            const float v = Vs[j][d];
#pragma unroll
            for (int r = 0; r < 8; ++r) acc[r] += S[i0 + r][j] * v;
        }
#pragma unroll
        for (int r = 0; r < 8; ++r)
            attn[(size_t)(s * N_ELEC + i0 + r) * DIM + h * HDIM + d] = acc[r];
    }
}

// ---------------------------------------------------------------------------
// LayerNorm over rows of 256; one block (256 thr) per row. In-place safe.
// ---------------------------------------------------------------------------
__global__ __launch_bounds__(256) void ln_k(
    const float* __restrict__ x, const float* __restrict__ scale,
    const float* __restrict__ bias, float* __restrict__ y)
{
    const int row = blockIdx.x;
    const int tid = threadIdx.x;
    const int lane = tid & 63;
    const int w = tid >> 6;

    __shared__ float ws1[4];
    __shared__ float ws2[4];

    float v = x[(size_t)row * DIM + tid];

    float s = v;
#pragma unroll
    for (int off = 32; off > 0; off >>= 1) s += __shfl_down(s, off, 64);
    if (lane == 0) ws1[w] = s;
    __syncthreads();
    const float mu = (ws1[0] + ws1[1] + ws1[2] + ws1[3]) * (1.0f / DIM);

    const float d = v - mu;
    float s2 = d * d;
#pragma unroll
    for (int off = 32; off > 0; off >>= 1) s2 += __shfl_down(s2, off, 64);
    if (lane == 0) ws2[w] = s2;
    __syncthreads();
    const float var = (ws2[0] + ws2[1] + ws2[2] + ws2[3]) * (1.0f / DIM);

    y[(size_t)row * DIM + tid] = d * rsqrtf(var + LN_EPS) * scale[tid] + bias[tid];
}

// ---------------------------------------------------------------------------
extern "C" void kernel_launch(void* const* d_in, const int* in_sizes, int n_in,
                              void* d_out, int out_size, void* d_ws, size_t ws_size,
                              hipStream_t stream)
{
    const float* h_one = (const float*)d_in[0];
    const float* W_qkv = (const float*)d_in[1];
    const float* W_out = (const float*)d_in[2];
    const float* ln1_s = (const float*)d_in[3];
    const float* ln1_b = (const float*)d_in[4];
    const float* W_mlp = (const float*)d_in[5];
    const float* b_mlp = (const float*)d_in[6];
    const float* ln2_s = (const float*)d_in[7];
    const float* ln2_b = (const float*)d_in[8];
    float* out = (float*)d_out;

    float* ws   = (float*)d_ws;
    float* qkv  = ws;                              // 4096*768
    float* attn = qkv + (size_t)NTOT * 3 * DIM;    // 4096*256
    float* h1   = attn + (size_t)NTOT * DIM;       // 4096*256
    float* h2   = attn;                            // alias: attn dead after out-proj

    // 1) qkv = h_one @ W_qkv          [4096,256]x[256,768]
    gemm_k<0><<<dim3(12, 64), 256, 0, stream>>>(h_one, W_qkv, nullptr, nullptr,
                                                qkv, NTOT, 3 * DIM, DIM);
    // 2) attention (block-diagonal, column softmax)
    attn_k<<<N_SYS * HEADS, 256, 0, stream>>>(qkv, attn);
    // 3) h1 = h_one + attn @ W_out
    gemm_k<1><<<dim3(4, 64), 256, 0, stream>>>(attn, W_out, h_one, nullptr,
                                               h1, NTOT, DIM, DIM);
    // 4) h1 = LN1(h1)   (in-place)
    ln_k<<<NTOT, 256, 0, stream>>>(h1, ln1_s, ln1_b, h1);
    // 5) h2 = h1 + silu(h1 @ W_mlp + b_mlp)
    gemm_k<2><<<dim3(4, 64), 256, 0, stream>>>(h1, W_mlp, h1, b_mlp,
                                               h2, NTOT, DIM, DIM);
    // 6) out = LN2(h2)
    ln_k<<<NTOT, 256, 0, stream>>>(h2, ln2_s, ln2_b, out);
}

// Round 2
// 60.580 us; speedup vs baseline: 1.4699x; 1.4699x over previous
//
#include <hip/hip_runtime.h>
#include <hip/hip_bf16.h>
#include <math.h>

// Problem constants (fixed by setup_inputs in the reference)
#define N_SYS   64
#define N_ELEC  64
#define NTOT    (N_SYS * N_ELEC)   // 4096
#define DIM     256
#define HEADS   8
#define HDIM    (DIM / HEADS)      // 32
#define LN_EPS  1e-6f

typedef __attribute__((ext_vector_type(8))) short bf16x8;
typedef __attribute__((ext_vector_type(4))) short short4v;
typedef __attribute__((ext_vector_type(4))) float f32x4;

static __device__ __forceinline__ short f2bf(float f) {
    __hip_bfloat16 h = __float2bfloat16(f);
    return *reinterpret_cast<short*>(&h);
}

// ---------------------------------------------------------------------------
// Prep: transpose-cast the 3 weight matrices f32 [K][N] -> bf16 [N][K].
// One 64x64 tile per block; 80 blocks total (48 qkv + 16 out + 16 mlp).
// ---------------------------------------------------------------------------
__global__ __launch_bounds__(256) void prep_k(
    const float* __restrict__ Wqkv, const float* __restrict__ Wout,
    const float* __restrict__ Wmlp, short* __restrict__ WqkvT,
    short* __restrict__ WoutT, short* __restrict__ WmlpT)
{
    __shared__ float t[64][65];
    const int b = blockIdx.x;
    const float* src; short* dst; int N, tile;
    if (b < 48)      { src = Wqkv; dst = WqkvT; N = 768; tile = b; }
    else if (b < 64) { src = Wout; dst = WoutT; N = 256; tile = b - 48; }
    else             { src = Wmlp; dst = WmlpT; N = 256; tile = b - 64; }
    const int K = 256;
    const int ntN = N / 64;
    const int tk = tile / ntN, tn = tile % ntN;
    const int tid = threadIdx.x;
#pragma unroll
    for (int it = 0; it < 4; ++it) {
        int idx = it * 256 + tid;
        int r = idx >> 4, c4 = (idx & 15) * 4;
        float4 v = *(const float4*)&src[(size_t)(tk * 64 + r) * N + tn * 64 + c4];
        t[r][c4 + 0] = v.x; t[r][c4 + 1] = v.y;
        t[r][c4 + 2] = v.z; t[r][c4 + 3] = v.w;
    }
    __syncthreads();
#pragma unroll
    for (int it = 0; it < 4; ++it) {
        int idx = it * 256 + tid;
        int r = idx >> 4, c4 = (idx & 15) * 4;   // r = local n, c4 = local k chunk
        short4v o;
        o[0] = f2bf(t[c4 + 0][r]); o[1] = f2bf(t[c4 + 1][r]);
        o[2] = f2bf(t[c4 + 2][r]); o[3] = f2bf(t[c4 + 3][r]);
        *(short4v*)&dst[(size_t)(tn * 64 + r) * K + tk * 64 + c4] = o;
    }
}

// ---------------------------------------------------------------------------
// MFMA GEMM: C[M,N] = A[M,K] @ B[K,N], B given pre-transposed bf16 [N][K].
// ABF=0: A is f32 (converted during staging). ABF=1: A is bf16.
// EPI 0: C = A@B ; EPI 1: C = res + A@B ; EPI 2: C = res + silu(A@B + bias)
// 128x128 tile, BK=64, 256 threads = 4 waves, each wave 64x64 via 4x4
// mfma_f32_16x16x32_bf16 fragments.
// ---------------------------------------------------------------------------
template <int EPI, int ABF>
__global__ __launch_bounds__(256) void mgemm_k(
    const void* __restrict__ Ain, const short* __restrict__ Bt,
    const float* __restrict__ res, const float* __restrict__ bias,
    float* __restrict__ C, int M, int N, int K)
{
    __shared__ short As[128][72];   // [m][k], 144B row pitch -> conflict-floor reads
    __shared__ short Bs[128][72];   // [n][k]

    const int tid = threadIdx.x;
    const int lane = tid & 63;
    const int w = tid >> 6;
    const int wm = (w >> 1) * 64;
    const int wn = (w & 1) * 64;
    const int bm = blockIdx.y * 128;
    const int bn = blockIdx.x * 128;
    const int l15 = lane & 15;
    const int l4 = lane >> 4;

    f32x4 acc[4][4] = {};

    for (int k0 = 0; k0 < K; k0 += 64) {
        __syncthreads();   // protect prior-iteration LDS reads
        if constexpr (ABF == 0) {
            const float* A = (const float*)Ain;
#pragma unroll
            for (int it = 0; it < 4; ++it) {
                int c = it * 256 + tid;
                int r = c >> 3, c8 = (c & 7) * 8;
                const float* src = &A[(size_t)(bm + r) * K + k0 + c8];
                float4 v0 = *(const float4*)src;
                float4 v1 = *(const float4*)(src + 4);
                bf16x8 o;
                o[0] = f2bf(v0.x); o[1] = f2bf(v0.y); o[2] = f2bf(v0.z); o[3] = f2bf(v0.w);
                o[4] = f2bf(v1.x); o[5] = f2bf(v1.y); o[6] = f2bf(v1.z); o[7] = f2bf(v1.w);
                *(bf16x8*)&As[r][c8] = o;
            }
        } else {
            const short* A = (const short*)Ain;
#pragma unroll
            for (int it = 0; it < 4; ++it) {
                int c = it * 256 + tid;
                int r = c >> 3, c8 = (c & 7) * 8;
                *(bf16x8*)&As[r][c8] = *(const bf16x8*)&A[(size_t)(bm + r) * K + k0 + c8];
            }
        }
#pragma unroll
        for (int it = 0; it < 4; ++it) {
            int c = it * 256 + tid;
            int r = c >> 3, c8 = (c & 7) * 8;
            *(bf16x8*)&Bs[r][c8] = *(const bf16x8*)&Bt[(size_t)(bn + r) * K + k0 + c8];
        }
        __syncthreads();

#pragma unroll
        for (int ki = 0; ki < 2; ++ki) {
            bf16x8 af[4], bfr[4];
#pragma unroll
            for (int i = 0; i < 4; ++i) {
                af[i]  = *(const bf16x8*)&As[wm + i * 16 + l15][ki * 32 + l4 * 8];
                bfr[i] = *(const bf16x8*)&Bs[wn + i * 16 + l15][ki * 32 + l4 * 8];
            }
#pragma unroll
            for (int i = 0; i < 4; ++i)
#pragma unroll
                for (int j = 0; j < 4; ++j)
                    acc[i][j] = __builtin_amdgcn_mfma_f32_16x16x32_bf16(
                        af[i], bfr[j], acc[i][j], 0, 0, 0);
        }
    }

    // Epilogue: C/D mapping col = lane&15, row = (lane>>4)*4 + reg (m89)
#pragma unroll
    for (int i = 0; i < 4; ++i) {
#pragma unroll
        for (int j = 0; j < 4; ++j) {
            const int row = bm + wm + i * 16 + l4 * 4 + j;
#pragma unroll
            for (int nn = 0; nn < 4; ++nn) {
                const int col = bn + wn + nn * 16 + l15;
                float v = acc[i][nn][j];
                if constexpr (EPI == 1) {
                    v += res[(size_t)row * N + col];
                } else if constexpr (EPI == 2) {
                    v += bias[col];
                    float sg = 1.0f / (1.0f + __expf(-v));
                    v = res[(size_t)row * N + col] + v * sg;
                }
                C[(size_t)row * N + col] = v;
            }
        }
    }
}

// ---------------------------------------------------------------------------
// Attention: one block per (system, head). 256 threads (4 waves). fp32 math,
// bf16 output (feeds the out-proj MFMA GEMM directly).
// S[i][j] = Q[i].K[j]/sqrt(32); softmax over i per column j; out = A^T-free PV.
// ---------------------------------------------------------------------------
__global__ __launch_bounds__(256) void attn_k(
    const float* __restrict__ qkv, short* __restrict__ attn)
{
    const int s = blockIdx.x >> 3;
    const int h = blockIdx.x & 7;

    __shared__ float Ks[64][36];
    __shared__ float Vs[64][36];
    __shared__ float S[64][65];
    __shared__ float red[8][64];

    const int tid = threadIdx.x;
    const int lane = tid & 63;
    const int w = tid >> 6;

    const float* base = qkv + (size_t)s * N_ELEC * (3 * DIM);

    for (int idx = tid; idx < 64 * 8; idx += 256) {
        const int r = idx >> 3;
        const int d4 = (idx & 7) * 4;
        float4 kv = *(const float4*)&base[(size_t)r * 768 + DIM + h * HDIM + d4];
        float4 vv = *(const float4*)&base[(size_t)r * 768 + 2 * DIM + h * HDIM + d4];
        *(float4*)&Ks[r][d4] = kv;
        *(float4*)&Vs[r][d4] = vv;
    }

    const int i = lane;
    float q[32];
#pragma unroll
    for (int d4 = 0; d4 < 32; d4 += 4) {
        float4 qv = *(const float4*)&base[(size_t)i * 768 + h * HDIM + d4];
        q[d4 + 0] = qv.x; q[d4 + 1] = qv.y; q[d4 + 2] = qv.z; q[d4 + 3] = qv.w;
    }
    __syncthreads();

    const float scale = 0.17677669529663687f;  // 1/sqrt(32)

#pragma unroll
    for (int jj = 0; jj < 16; ++jj) {
        const int j = w * 16 + jj;
        float acc = 0.0f;
#pragma unroll
        for (int d = 0; d < 32; d += 4) {
            float4 kv = *(const float4*)&Ks[j][d];
            acc += q[d] * kv.x + q[d + 1] * kv.y + q[d + 2] * kv.z + q[d + 3] * kv.w;
        }
        S[i][j] = acc * scale;
    }
    __syncthreads();

    {
        const int j = lane;
        const int r0 = w * 16;
        float m = -INFINITY;
#pragma unroll
        for (int r = 0; r < 16; ++r) m = fmaxf(m, S[r0 + r][j]);
        red[w][j] = m;
        __syncthreads();
        const float fm = fmaxf(fmaxf(red[0][j], red[1][j]), fmaxf(red[2][j], red[3][j]));
        float sum = 0.0f;
#pragma unroll
        for (int r = 0; r < 16; ++r) {
            float e = __expf(S[r0 + r][j] - fm);
            S[r0 + r][j] = e;
            sum += e;
        }
        red[4 + w][j] = sum;
        __syncthreads();
        const float inv = 1.0f / (red[4][j] + red[5][j] + red[6][j] + red[7][j]);
#pragma unroll
        for (int r = 0; r < 16; ++r) S[r0 + r][j] *= inv;
    }
    __syncthreads();

    {
        const int d = tid & 31;
        const int i0 = (tid >> 5) * 8;
        float acc[8] = {};
        for (int j = 0; j < 64; ++j) {
            const float v = Vs[j][d];
#pragma unroll
            for (int r = 0; r < 8; ++r) acc[r] += S[i0 + r][j] * v;
        }
#pragma unroll
        for (int r = 0; r < 8; ++r)
            attn[(size_t)(s * N_ELEC + i0 + r) * DIM + h * HDIM + d] = f2bf(acc[r]);
    }
}

// ---------------------------------------------------------------------------
// LayerNorm: one wave per row (DIM=256, float4/lane), 4 rows per block.
// Optional secondary bf16 output (feeds next MFMA GEMM).
// ---------------------------------------------------------------------------
__global__ __launch_bounds__(256) void ln_k(
    const float* __restrict__ x, const float* __restrict__ sc,
    const float* __restrict__ bi, float* __restrict__ y, short* __restrict__ ybf)
{
    const int row = blockIdx.x * 4 + (threadIdx.x >> 6);
    const int lane = threadIdx.x & 63;

    float4 v = *(const float4*)&x[(size_t)row * DIM + lane * 4];
    float s = v.x + v.y + v.z + v.w;
#pragma unroll
    for (int off = 32; off > 0; off >>= 1) s += __shfl_xor(s, off, 64);
    const float mu = s * (1.0f / DIM);

    const float dx = v.x - mu, dy = v.y - mu, dz = v.z - mu, dw = v.w - mu;
    float s2 = dx * dx + dy * dy + dz * dz + dw * dw;
#pragma unroll
    for (int off = 32; off > 0; off >>= 1) s2 += __shfl_xor(s2, off, 64);
    const float inv = rsqrtf(s2 * (1.0f / DIM) + LN_EPS);

    float4 s4 = *(const float4*)&sc[lane * 4];
    float4 b4 = *(const float4*)&bi[lane * 4];
    float4 o;
    o.x = dx * inv * s4.x + b4.x;
    o.y = dy * inv * s4.y + b4.y;
    o.z = dz * inv * s4.z + b4.z;
    o.w = dw * inv * s4.w + b4.w;
    *(float4*)&y[(size_t)row * DIM + lane * 4] = o;
    if (ybf) {
        short4v ob;
        ob[0] = f2bf(o.x); ob[1] = f2bf(o.y); ob[2] = f2bf(o.z); ob[3] = f2bf(o.w);
        *(short4v*)&ybf[(size_t)row * DIM + lane * 4] = ob;
    }
}

// ---------------------------------------------------------------------------
extern "C" void kernel_launch(void* const* d_in, const int* in_sizes, int n_in,
                              void* d_out, int out_size, void* d_ws, size_t ws_size,
                              hipStream_t stream)
{
    const float* h_one = (const float*)d_in[0];
    const float* W_qkv = (const float*)d_in[1];
    const float* W_out = (const float*)d_in[2];
    const float* ln1_s = (const float*)d_in[3];
    const float* ln1_b = (const float*)d_in[4];
    const float* W_mlp = (const float*)d_in[5];
    const float* b_mlp = (const float*)d_in[6];
    const float* ln2_s = (const float*)d_in[7];
    const float* ln2_b = (const float*)d_in[8];
    float* out = (float*)d_out;

    char* ws = (char*)d_ws;
    float* qkv    = (float*)ws;                                   // 4096*768 f32 = 12.58MB
    short* attn_bf = (short*)(ws + 12582912);                     // 4096*256 bf16 = 2MB
    float* h1     = (float*)(ws + 12582912 + 2097152);            // 4MB
    short* h1bf   = (short*)(ws + 12582912 + 2097152 + 4194304);  // 2MB
    short* WqkvT  = (short*)(ws + 12582912 + 2097152 + 4194304 + 2097152);
    short* WoutT  = WqkvT + 768 * 256;
    short* WmlpT  = WoutT + 256 * 256;
    float* h2     = qkv;   // qkv dead after attn_k

    // 0) weights -> bf16 [N][K]
    prep_k<<<80, 256, 0, stream>>>(W_qkv, W_out, W_mlp, WqkvT, WoutT, WmlpT);
    // 1) qkv = h_one @ W_qkv
    mgemm_k<0, 0><<<dim3(6, 32), 256, 0, stream>>>(h_one, WqkvT, nullptr, nullptr,
                                                   qkv, NTOT, 3 * DIM, DIM);
    // 2) attention (block-diagonal, column softmax), bf16 out
    attn_k<<<N_SYS * HEADS, 256, 0, stream>>>(qkv, attn_bf);
    // 3) h1 = h_one + attn @ W_out
    mgemm_k<1, 1><<<dim3(2, 32), 256, 0, stream>>>(attn_bf, WoutT, h_one, nullptr,
                                                   h1, NTOT, DIM, DIM);
    // 4) h1 = LN1(h1) (in-place) + bf16 copy
    ln_k<<<NTOT / 4, 256, 0, stream>>>(h1, ln1_s, ln1_b, h1, h1bf);
    // 5) h2 = h1 + silu(h1bf @ W_mlp + b_mlp)
    mgemm_k<2, 1><<<dim3(2, 32), 256, 0, stream>>>(h1bf, WmlpT, h1, b_mlp,
                                                   h2, NTOT, DIM, DIM);
    // 6) out = LN2(h2)
    ln_k<<<NTOT / 4, 256, 0, stream>>>(h2, ln2_s, ln2_b, out, nullptr);
}

// Round 3
// 31.013 us; speedup vs baseline: 2.8713x; 1.9534x over previous
//
#include <hip/hip_runtime.h>
#include <hip/hip_bf16.h>
#include <math.h>

#define N_SYS   64
#define N_ELEC  64
#define NTOT    (N_SYS * N_ELEC)   // 4096
#define DIM     256
#define HEADS   8
#define HDIM    32
#define LN_EPS  1e-6f

typedef __attribute__((ext_vector_type(8))) short bf16x8;
typedef __attribute__((ext_vector_type(4))) short short4v;
typedef __attribute__((ext_vector_type(4))) float f32x4;

static __device__ __forceinline__ short f2bf(float f) {
    __hip_bfloat16 h = __float2bfloat16(f);
    return *reinterpret_cast<short*>(&h);
}

// ---------------------------------------------------------------------------
// Prep: transpose-cast weights f32 [K][N] -> bf16 [N][K]. 80 blocks.
// ---------------------------------------------------------------------------
__global__ __launch_bounds__(256) void prep_k(
    const float* __restrict__ Wqkv, const float* __restrict__ Wout,
    const float* __restrict__ Wmlp, short* __restrict__ WqkvT,
    short* __restrict__ WoutT, short* __restrict__ WmlpT)
{
    __shared__ float t[64][65];
    const int b = blockIdx.x;
    const float* src; short* dst; int N, tile;
    if (b < 48)      { src = Wqkv; dst = WqkvT; N = 768; tile = b; }
    else if (b < 64) { src = Wout; dst = WoutT; N = 256; tile = b - 48; }
    else             { src = Wmlp; dst = WmlpT; N = 256; tile = b - 64; }
    const int K = 256;
    const int ntN = N / 64;
    const int tk = tile / ntN, tn = tile % ntN;
    const int tid = threadIdx.x;
#pragma unroll
    for (int it = 0; it < 4; ++it) {
        int idx = it * 256 + tid;
        int r = idx >> 4, c4 = (idx & 15) * 4;
        float4 v = *(const float4*)&src[(size_t)(tk * 64 + r) * N + tn * 64 + c4];
        t[r][c4 + 0] = v.x; t[r][c4 + 1] = v.y;
        t[r][c4 + 2] = v.z; t[r][c4 + 3] = v.w;
    }
    __syncthreads();
#pragma unroll
    for (int it = 0; it < 4; ++it) {
        int idx = it * 256 + tid;
        int r = idx >> 4, c4 = (idx & 15) * 4;
        short4v o;
        o[0] = f2bf(t[c4 + 0][r]); o[1] = f2bf(t[c4 + 1][r]);
        o[2] = f2bf(t[c4 + 2][r]); o[3] = f2bf(t[c4 + 3][r]);
        *(short4v*)&dst[(size_t)(tn * 64 + r) * K + tk * 64 + c4] = o;
    }
}

// ---------------------------------------------------------------------------
// K1: fused qkv-slice GEMM + attention for one (system, head).
// Grid 512 = s*8+h, 256 threads = 4 waves. All-MFMA.
//   qkv slice: [64 rows] x [96 cols: Q(32)|K(32)|V(32)], K=256
//   S = Q@K^T / sqrt(32); softmax over rows i per column j; attn = P@V.
// ---------------------------------------------------------------------------
__global__ __launch_bounds__(256) void k1_qkv_attn(
    const float* __restrict__ h_one, const short* __restrict__ WqkvT,
    short* __restrict__ attn)
{
    const int s = blockIdx.x >> 3;
    const int h = blockIdx.x & 7;

    __shared__ short Ha[64][72];    // A k-slice (bf16 of h_one rows)
    __shared__ short Bs[96][72];    // B k-slice (WqkvT rows for this head)
    __shared__ short Qs[64][40];    // Q [i][d]
    __shared__ short Ks[64][40];    // K [j][d]
    __shared__ short Vt[32][72];    // V^T [d][j]
    __shared__ float Sm[64][68];    // scores
    __shared__ short Pm[64][72];    // P bf16
    __shared__ float red[8][64];

    const int tid = threadIdx.x;
    const int lane = tid & 63;
    const int w = tid >> 6;
    const int l15 = lane & 15;
    const int l4 = lane >> 4;

    const float* Abase = h_one + (size_t)s * 64 * 256;
    const short* Bbase = WqkvT + (size_t)h * 32 * 256;

    f32x4 acc[6] = {};

    for (int k0 = 0; k0 < 256; k0 += 64) {
        __syncthreads();
#pragma unroll
        for (int it = 0; it < 2; ++it) {
            int c = it * 256 + tid;          // 0..511 : 64 rows x 8 chunks
            int r = c >> 3, c8 = (c & 7) * 8;
            const float* src = &Abase[(size_t)r * 256 + k0 + c8];
            float4 v0 = *(const float4*)src;
            float4 v1 = *(const float4*)(src + 4);
            bf16x8 o;
            o[0] = f2bf(v0.x); o[1] = f2bf(v0.y); o[2] = f2bf(v0.z); o[3] = f2bf(v0.w);
            o[4] = f2bf(v1.x); o[5] = f2bf(v1.y); o[6] = f2bf(v1.z); o[7] = f2bf(v1.w);
            *(bf16x8*)&Ha[r][c8] = o;
        }
#pragma unroll
        for (int it = 0; it < 3; ++it) {
            int c = it * 256 + tid;          // 0..767 : 96 rows x 8 chunks
            int r = c >> 3, c8 = (c & 7) * 8;
            int g = r >> 5, nl = r & 31;     // group (Q/K/V), row within
            *(bf16x8*)&Bs[r][c8] =
                *(const bf16x8*)&Bbase[((size_t)g * 256 + nl) * 256 + k0 + c8];
        }
        __syncthreads();
#pragma unroll
        for (int ki = 0; ki < 2; ++ki) {
            bf16x8 af = *(const bf16x8*)&Ha[w * 16 + l15][ki * 32 + l4 * 8];
#pragma unroll
            for (int nf = 0; nf < 6; ++nf) {
                bf16x8 bf = *(const bf16x8*)&Bs[nf * 16 + l15][ki * 32 + l4 * 8];
                acc[nf] = __builtin_amdgcn_mfma_f32_16x16x32_bf16(af, bf, acc[nf], 0, 0, 0);
            }
        }
    }

    // scatter Q, K, V^T to LDS (C-layout: row = w*16 + l4*4 + j, col = nf*16 + l15)
#pragma unroll
    for (int nf = 0; nf < 6; ++nf) {
        int c = nf * 16 + l15;
#pragma unroll
        for (int j = 0; j < 4; ++j) {
            int row = w * 16 + l4 * 4 + j;
            short v = f2bf(acc[nf][j]);
            if (c < 32)       Qs[row][c] = v;
            else if (c < 64)  Ks[row][c - 32] = v;
            else              Vt[c - 64][row] = v;
        }
    }
    __syncthreads();

    // S = Q @ K^T (wave w: rows [w*16, +16), all 64 cols), scaled
    {
        const float scale = 0.17677669529663687f;  // 1/sqrt(32)
        f32x4 sacc[4] = {};
        bf16x8 aq = *(const bf16x8*)&Qs[w * 16 + l15][l4 * 8];
#pragma unroll
        for (int nf = 0; nf < 4; ++nf) {
            bf16x8 bk = *(const bf16x8*)&Ks[nf * 16 + l15][l4 * 8];
            sacc[nf] = __builtin_amdgcn_mfma_f32_16x16x32_bf16(aq, bk, sacc[nf], 0, 0, 0);
        }
#pragma unroll
        for (int nf = 0; nf < 4; ++nf)
#pragma unroll
            for (int j = 0; j < 4; ++j)
                Sm[w * 16 + l4 * 4 + j][nf * 16 + l15] = sacc[nf][j] * scale;
    }
    __syncthreads();

    // column softmax (over i): thread (w, lane): col j=lane, rows [w*16, +16)
    {
        const int j = lane;
        const int r0 = w * 16;
        float m = -INFINITY;
#pragma unroll
        for (int r = 0; r < 16; ++r) m = fmaxf(m, Sm[r0 + r][j]);
        red[w][j] = m;
        __syncthreads();
        const float fm = fmaxf(fmaxf(red[0][j], red[1][j]), fmaxf(red[2][j], red[3][j]));
        float e[16];
        float sum = 0.0f;
#pragma unroll
        for (int r = 0; r < 16; ++r) {
            e[r] = __expf(Sm[r0 + r][j] - fm);
            sum += e[r];
        }
        red[4 + w][j] = sum;
        __syncthreads();
        const float inv = 1.0f / (red[4][j] + red[5][j] + red[6][j] + red[7][j]);
#pragma unroll
        for (int r = 0; r < 16; ++r) Pm[r0 + r][j] = f2bf(e[r] * inv);
    }
    __syncthreads();

    // attn = P @ V : wave w rows [w*16,+16), cols d 0..31
    {
        f32x4 pv[2] = {};
#pragma unroll
        for (int ki = 0; ki < 2; ++ki) {
            bf16x8 ap = *(const bf16x8*)&Pm[w * 16 + l15][ki * 32 + l4 * 8];
#pragma unroll
            for (int nf = 0; nf < 2; ++nf) {
                bf16x8 bv = *(const bf16x8*)&Vt[nf * 16 + l15][ki * 32 + l4 * 8];
                pv[nf] = __builtin_amdgcn_mfma_f32_16x16x32_bf16(ap, bv, pv[nf], 0, 0, 0);
            }
        }
#pragma unroll
        for (int nf = 0; nf < 2; ++nf)
#pragma unroll
            for (int j = 0; j < 4; ++j) {
                int row = w * 16 + l4 * 4 + j;
                int d = nf * 16 + l15;
                attn[(size_t)(s * 64 + row) * 256 + h * 32 + d] = f2bf(pv[nf][j]);
            }
    }
}

// ---------------------------------------------------------------------------
// K2: fused tail for 16 rows: out-proj+residual, LN1, MLP(silu)+residual, LN2.
// Grid 256 blocks x 512 threads (8 waves). B-matrices ([n][k] bf16) read as
// MFMA fragments directly from global (L2-resident).
// ---------------------------------------------------------------------------
__global__ __launch_bounds__(512) void k2_tail(
    const short* __restrict__ attnbf, const short* __restrict__ WoutT,
    const short* __restrict__ WmlpT, const float* __restrict__ h_one,
    const float* __restrict__ b_mlp,
    const float* __restrict__ ln1_s, const float* __restrict__ ln1_b,
    const float* __restrict__ ln2_s, const float* __restrict__ ln2_b,
    float* __restrict__ out)
{
    const int r0 = blockIdx.x * 16;

    __shared__ short Abf[16][264];
    __shared__ float H1[16][260];
    __shared__ short L1[16][264];

    const int tid = threadIdx.x;
    const int lane = tid & 63;
    const int w = tid >> 6;           // 0..7
    const int l15 = lane & 15;
    const int l4 = lane >> 4;

    // stage attn rows (bf16)
    {
        int r = tid >> 5, c8 = (tid & 31) * 8;
        *(bf16x8*)&Abf[r][c8] = *(const bf16x8*)&attnbf[(size_t)(r0 + r) * 256 + c8];
    }
    __syncthreads();

    // GEMM1: wave w covers cols [w*32, +32) (2 n-frags), M=16, K=256
    f32x4 acc[2] = {};
    for (int k0 = 0; k0 < 256; k0 += 32) {
        bf16x8 af = *(const bf16x8*)&Abf[l15][k0 + l4 * 8];
#pragma unroll
        for (int nf = 0; nf < 2; ++nf) {
            int n = w * 32 + nf * 16 + l15;
            bf16x8 bf = *(const bf16x8*)&WoutT[(size_t)n * 256 + k0 + l4 * 8];
            acc[nf] = __builtin_amdgcn_mfma_f32_16x16x32_bf16(af, bf, acc[nf], 0, 0, 0);
        }
    }
#pragma unroll
    for (int nf = 0; nf < 2; ++nf) {
        int col = w * 32 + nf * 16 + l15;
#pragma unroll
        for (int j = 0; j < 4; ++j) {
            int row = l4 * 4 + j;
            H1[row][col] = acc[nf][j] + h_one[(size_t)(r0 + row) * 256 + col];
        }
    }
    __syncthreads();

    // LN1: wave w -> rows w*2, w*2+1; writes H1 (f32, residual) + L1 (bf16 A)
    {
        float4 sc = *(const float4*)&ln1_s[lane * 4];
        float4 bi = *(const float4*)&ln1_b[lane * 4];
#pragma unroll
        for (int rr = 0; rr < 2; ++rr) {
            int row = w * 2 + rr;
            float4 v = *(const float4*)&H1[row][lane * 4];
            float su = v.x + v.y + v.z + v.w;
#pragma unroll
            for (int off = 32; off > 0; off >>= 1) su += __shfl_xor(su, off, 64);
            float mu = su * (1.0f / 256.0f);
            float dx = v.x - mu, dy = v.y - mu, dz = v.z - mu, dw = v.w - mu;
            float s2 = dx * dx + dy * dy + dz * dz + dw * dw;
#pragma unroll
            for (int off = 32; off > 0; off >>= 1) s2 += __shfl_xor(s2, off, 64);
            float inv = rsqrtf(s2 * (1.0f / 256.0f) + LN_EPS);
            float4 o;
            o.x = dx * inv * sc.x + bi.x;
            o.y = dy * inv * sc.y + bi.y;
            o.z = dz * inv * sc.z + bi.z;
            o.w = dw * inv * sc.w + bi.w;
            *(float4*)&H1[row][lane * 4] = o;
            short4v ob;
            ob[0] = f2bf(o.x); ob[1] = f2bf(o.y); ob[2] = f2bf(o.z); ob[3] = f2bf(o.w);
            *(short4v*)&L1[row][lane * 4] = ob;
        }
    }
    __syncthreads();

    // GEMM2: h2 = H1 + silu(L1 @ WmlpT + b_mlp)
    f32x4 acc2[2] = {};
    for (int k0 = 0; k0 < 256; k0 += 32) {
        bf16x8 af = *(const bf16x8*)&L1[l15][k0 + l4 * 8];
#pragma unroll
        for (int nf = 0; nf < 2; ++nf) {
            int n = w * 32 + nf * 16 + l15;
            bf16x8 bf = *(const bf16x8*)&WmlpT[(size_t)n * 256 + k0 + l4 * 8];
            acc2[nf] = __builtin_amdgcn_mfma_f32_16x16x32_bf16(af, bf, acc2[nf], 0, 0, 0);
        }
    }
#pragma unroll
    for (int nf = 0; nf < 2; ++nf) {
        int col = w * 32 + nf * 16 + l15;
        float bm = b_mlp[col];
#pragma unroll
        for (int j = 0; j < 4; ++j) {
            int row = l4 * 4 + j;
            float v = acc2[nf][j] + bm;
            float sg = 1.0f / (1.0f + __expf(-v));
            H1[row][col] = H1[row][col] + v * sg;   // same-lane RMW
        }
    }
    __syncthreads();

    // LN2 -> out (f32)
    {
        float4 sc = *(const float4*)&ln2_s[lane * 4];
        float4 bi = *(const float4*)&ln2_b[lane * 4];
#pragma unroll
        for (int rr = 0; rr < 2; ++rr) {
            int row = w * 2 + rr;
            float4 v = *(const float4*)&H1[row][lane * 4];
            float su = v.x + v.y + v.z + v.w;
#pragma unroll
            for (int off = 32; off > 0; off >>= 1) su += __shfl_xor(su, off, 64);
            float mu = su * (1.0f / 256.0f);
            float dx = v.x - mu, dy = v.y - mu, dz = v.z - mu, dw = v.w - mu;
            float s2 = dx * dx + dy * dy + dz * dz + dw * dw;
#pragma unroll
            for (int off = 32; off > 0; off >>= 1) s2 += __shfl_xor(s2, off, 64);
            float inv = rsqrtf(s2 * (1.0f / 256.0f) + LN_EPS);
            float4 o;
            o.x = dx * inv * sc.x + bi.x;
            o.y = dy * inv * sc.y + bi.y;
            o.z = dz * inv * sc.z + bi.z;
            o.w = dw * inv * sc.w + bi.w;
            *(float4*)&out[(size_t)(r0 + row) * 256 + lane * 4] = o;
        }
    }
}

// ---------------------------------------------------------------------------
extern "C" void kernel_launch(void* const* d_in, const int* in_sizes, int n_in,
                              void* d_out, int out_size, void* d_ws, size_t ws_size,
                              hipStream_t stream)
{
    const float* h_one = (const float*)d_in[0];
    const float* W_qkv = (const float*)d_in[1];
    const float* W_out = (const float*)d_in[2];
    const float* ln1_s = (const float*)d_in[3];
    const float* ln1_b = (const float*)d_in[4];
    const float* W_mlp = (const float*)d_in[5];
    const float* b_mlp = (const float*)d_in[6];
    const float* ln2_s = (const float*)d_in[7];
    const float* ln2_b = (const float*)d_in[8];
    float* out = (float*)d_out;

    char* ws = (char*)d_ws;
    short* attn_bf = (short*)ws;                        // 4096*256 bf16 = 2MB
    short* WqkvT   = (short*)(ws + 2097152);            // 768*256 bf16
    short* WoutT   = WqkvT + 768 * 256;
    short* WmlpT   = WoutT + 256 * 256;

    prep_k<<<80, 256, 0, stream>>>(W_qkv, W_out, W_mlp, WqkvT, WoutT, WmlpT);
    k1_qkv_attn<<<N_SYS * HEADS, 256, 0, stream>>>(h_one, WqkvT, attn_bf);
    k2_tail<<<NTOT / 16, 512, 0, stream>>>(attn_bf, WoutT, WmlpT, h_one, b_mlp,
                                           ln1_s, ln1_b, ln2_s, ln2_b, out);
}

// Round 4
// 27.780 us; speedup vs baseline: 3.2055x; 1.1164x over previous
//
#include <hip/hip_runtime.h>
#include <hip/hip_bf16.h>
#include <math.h>

#define N_SYS   64
#define N_ELEC  64
#define NTOT    (N_SYS * N_ELEC)   // 4096
#define DIM     256
#define HEADS   8
#define LN_EPS  1e-6f

typedef __attribute__((ext_vector_type(8))) short bf16x8;
typedef __attribute__((ext_vector_type(4))) short short4v;
typedef __attribute__((ext_vector_type(4))) float f32x4;

static __device__ __forceinline__ short f2bf(float f) {
    __hip_bfloat16 h = __float2bfloat16(f);
    return *reinterpret_cast<short*>(&h);
}

// ---------------------------------------------------------------------------
// K1: blocks 0..511 : fused qkv-slice GEMM + attention for one (system, head).
//     blocks 512..543: transpose-cast Wout/Wmlp f32 [K][N] -> bf16 [N][K]
//                      (consumed by K2; no dependency inside K1).
// 256 threads = 4 waves.
// ---------------------------------------------------------------------------
__global__ __launch_bounds__(256) void k1_qkv_attn(
    const float* __restrict__ h_one, const float* __restrict__ W_qkv,
    const float* __restrict__ Wout, const float* __restrict__ Wmlp,
    short* __restrict__ attn, short* __restrict__ WoutT,
    short* __restrict__ WmlpT)
{
    const int tid = threadIdx.x;

    if (blockIdx.x >= 512) {
        // ---- weight transpose tiles (64x64), coalesced read, scattered write
        const int b2 = blockIdx.x - 512;
        const float* src = (b2 < 16) ? Wout : Wmlp;
        short* dst = (b2 < 16) ? WoutT : WmlpT;
        const int tile = b2 & 15;
        const int tk = (tile >> 2) * 64, tn = (tile & 3) * 64;
#pragma unroll
        for (int p = 0; p < 4; ++p) {
            int idx = p * 256 + tid;
            int kk = idx >> 4, n4 = (idx & 15) * 4;
            float4 v = *(const float4*)&src[(size_t)(tk + kk) * 256 + tn + n4];
            dst[(size_t)(tn + n4 + 0) * 256 + tk + kk] = f2bf(v.x);
            dst[(size_t)(tn + n4 + 1) * 256 + tk + kk] = f2bf(v.y);
            dst[(size_t)(tn + n4 + 2) * 256 + tk + kk] = f2bf(v.z);
            dst[(size_t)(tn + n4 + 3) * 256 + tk + kk] = f2bf(v.w);
        }
        return;
    }

    const int s = blockIdx.x >> 3;
    const int h = blockIdx.x & 7;

    __shared__ short Ha[64][72];    // A k-slice (bf16 of h_one rows)
    __shared__ short Bs[96][72];    // B^T k-slice: Bs[n][k] = W_qkv[k][col(n)]
    __shared__ short Qs[64][40];    // Q [i][d]   (80B rows, 16B aligned)
    __shared__ short Ks[64][40];    // K [j][d]
    __shared__ short Vt[32][72];    // V^T [d][j]
    __shared__ short Pm[64][72];    // P bf16 [i][j]
    __shared__ float redM[64][4];   // [col][wave] partial max
    __shared__ float redS[64][4];   // [col][wave] partial sum

    const int lane = tid & 63;
    const int w = tid >> 6;
    const int l15 = lane & 15;
    const int l4 = lane >> 4;

    const float* Abase = h_one + (size_t)s * 64 * 256;
    const int bkk = tid >> 2;       // 0..63 : k row within step
    const int btt = tid & 3;        // float4 chunk phase

    f32x4 acc[6] = {};

    for (int k0 = 0; k0 < 256; k0 += 64) {
        __syncthreads();            // protect prior-iteration LDS reads
        // A: 64x64 f32 -> bf16, linear rows
#pragma unroll
        for (int it = 0; it < 2; ++it) {
            int c = it * 256 + tid;
            int r = c >> 3, c8 = (c & 7) * 8;
            const float* srcp = &Abase[(size_t)r * 256 + k0 + c8];
            float4 v0 = *(const float4*)srcp;
            float4 v1 = *(const float4*)(srcp + 4);
            bf16x8 o;
            o[0] = f2bf(v0.x); o[1] = f2bf(v0.y); o[2] = f2bf(v0.z); o[3] = f2bf(v0.w);
            o[4] = f2bf(v1.x); o[5] = f2bf(v1.y); o[6] = f2bf(v1.z); o[7] = f2bf(v1.w);
            *(bf16x8*)&Ha[r][c8] = o;
        }
        // B: W_qkv rows (k0+bkk), head-h columns of Q|K|V, transposed into Bs
#pragma unroll
        for (int q = 0; q < 6; ++q) {
            int c = btt + q * 4;            // float4 chunk 0..23
            int g = c >> 3;                 // 0=Q, 1=K, 2=V
            int c4 = (c & 7) * 4;           // col offset within 32
            float4 v = *(const float4*)&W_qkv[(size_t)(k0 + bkk) * 768 + g * 256 + h * 32 + c4];
            Bs[g * 32 + c4 + 0][bkk] = f2bf(v.x);
            Bs[g * 32 + c4 + 1][bkk] = f2bf(v.y);
            Bs[g * 32 + c4 + 2][bkk] = f2bf(v.z);
            Bs[g * 32 + c4 + 3][bkk] = f2bf(v.w);
        }
        __syncthreads();
#pragma unroll
        for (int ki = 0; ki < 2; ++ki) {
            bf16x8 af = *(const bf16x8*)&Ha[w * 16 + l15][ki * 32 + l4 * 8];
#pragma unroll
            for (int nf = 0; nf < 6; ++nf) {
                bf16x8 bfv = *(const bf16x8*)&Bs[nf * 16 + l15][ki * 32 + l4 * 8];
                acc[nf] = __builtin_amdgcn_mfma_f32_16x16x32_bf16(af, bfv, acc[nf], 0, 0, 0);
            }
        }
    }

    // scatter Q, K, V^T to LDS (C-layout: row = w*16 + l4*4 + j, col = nf*16 + l15)
#pragma unroll
    for (int nf = 0; nf < 6; ++nf) {
        int c = nf * 16 + l15;
#pragma unroll
        for (int j = 0; j < 4; ++j) {
            int row = w * 16 + l4 * 4 + j;
            short v = f2bf(acc[nf][j]);
            if (c < 32)       Qs[row][c] = v;
            else if (c < 64)  Ks[row][c - 32] = v;
            else              Vt[c - 64][row] = v;
        }
    }
    __syncthreads();

    // S = Q @ K^T (wave w: rows [w*16,+16), all 64 cols), then column softmax
    const float scale = 0.17677669529663687f;  // 1/sqrt(32)
    f32x4 sacc[4] = {};
    {
        bf16x8 aq = *(const bf16x8*)&Qs[w * 16 + l15][l4 * 8];
#pragma unroll
        for (int nf = 0; nf < 4; ++nf) {
            bf16x8 bk = *(const bf16x8*)&Ks[nf * 16 + l15][l4 * 8];
            sacc[nf] = __builtin_amdgcn_mfma_f32_16x16x32_bf16(aq, bk, sacc[nf], 0, 0, 0);
        }
    }
    float m[4];
#pragma unroll
    for (int nf = 0; nf < 4; ++nf) {
        sacc[nf] *= scale;
        float mm = fmaxf(fmaxf(sacc[nf][0], sacc[nf][1]), fmaxf(sacc[nf][2], sacc[nf][3]));
        mm = fmaxf(mm, __shfl_xor(mm, 16, 64));
        mm = fmaxf(mm, __shfl_xor(mm, 32, 64));
        m[nf] = mm;
    }
    if (l4 == 0) {
#pragma unroll
        for (int nf = 0; nf < 4; ++nf) redM[nf * 16 + l15][w] = m[nf];
    }
    __syncthreads();
#pragma unroll
    for (int nf = 0; nf < 4; ++nf) {
        float4 mw = *(const float4*)&redM[nf * 16 + l15][0];
        m[nf] = fmaxf(fmaxf(mw.x, mw.y), fmaxf(mw.z, mw.w));
    }
    float sm[4];
#pragma unroll
    for (int nf = 0; nf < 4; ++nf) {
#pragma unroll
        for (int j = 0; j < 4; ++j) sacc[nf][j] = __expf(sacc[nf][j] - m[nf]);
        float ss = sacc[nf][0] + sacc[nf][1] + sacc[nf][2] + sacc[nf][3];
        ss += __shfl_xor(ss, 16, 64);
        ss += __shfl_xor(ss, 32, 64);
        sm[nf] = ss;
    }
    if (l4 == 0) {
#pragma unroll
        for (int nf = 0; nf < 4; ++nf) redS[nf * 16 + l15][w] = sm[nf];
    }
    __syncthreads();
#pragma unroll
    for (int nf = 0; nf < 4; ++nf) {
        float4 sw = *(const float4*)&redS[nf * 16 + l15][0];
        float inv = 1.0f / (sw.x + sw.y + sw.z + sw.w);
#pragma unroll
        for (int j = 0; j < 4; ++j)
            Pm[w * 16 + l4 * 4 + j][nf * 16 + l15] = f2bf(sacc[nf][j] * inv);
    }
    __syncthreads();   // Pm/Vt visibility for PV

    // attn = P @ V : wave w rows [w*16,+16), cols d 0..31
    f32x4 pv[2] = {};
#pragma unroll
    for (int ki = 0; ki < 2; ++ki) {
        bf16x8 ap = *(const bf16x8*)&Pm[w * 16 + l15][ki * 32 + l4 * 8];
#pragma unroll
        for (int nf = 0; nf < 2; ++nf) {
            bf16x8 bv = *(const bf16x8*)&Vt[nf * 16 + l15][ki * 32 + l4 * 8];
            pv[nf] = __builtin_amdgcn_mfma_f32_16x16x32_bf16(ap, bv, pv[nf], 0, 0, 0);
        }
    }
#pragma unroll
    for (int nf = 0; nf < 2; ++nf)
#pragma unroll
        for (int j = 0; j < 4; ++j)
            attn[(size_t)(s * 64 + w * 16 + l4 * 4 + j) * 256 + h * 32 + nf * 16 + l15]
                = f2bf(pv[nf][j]);
}

// ---------------------------------------------------------------------------
// K2: fused tail for 16 rows: out-proj+residual, LN1, MLP(silu)+residual, LN2.
// Grid 256 blocks x 512 threads (8 waves). Weight fragments read from global.
// ---------------------------------------------------------------------------
__global__ __launch_bounds__(512) void k2_tail(
    const short* __restrict__ attnbf, const short* __restrict__ WoutT,
    const short* __restrict__ WmlpT, const float* __restrict__ h_one,
    const float* __restrict__ b_mlp,
    const float* __restrict__ ln1_s, const float* __restrict__ ln1_b,
    const float* __restrict__ ln2_s, const float* __restrict__ ln2_b,
    float* __restrict__ out)
{
    const int r0 = blockIdx.x * 16;

    __shared__ short Abf[16][264];
    __shared__ float H1[16][260];
    __shared__ short L1[16][264];

    const int tid = threadIdx.x;
    const int lane = tid & 63;
    const int w = tid >> 6;           // 0..7
    const int l15 = lane & 15;
    const int l4 = lane >> 4;

    {
        int r = tid >> 5, c8 = (tid & 31) * 8;
        *(bf16x8*)&Abf[r][c8] = *(const bf16x8*)&attnbf[(size_t)(r0 + r) * 256 + c8];
    }
    __syncthreads();

    // GEMM1: wave w covers cols [w*32, +32), M=16, K=256
    f32x4 acc[2] = {};
    for (int k0 = 0; k0 < 256; k0 += 32) {
        bf16x8 af = *(const bf16x8*)&Abf[l15][k0 + l4 * 8];
#pragma unroll
        for (int nf = 0; nf < 2; ++nf) {
            int n = w * 32 + nf * 16 + l15;
            bf16x8 bf = *(const bf16x8*)&WoutT[(size_t)n * 256 + k0 + l4 * 8];
            acc[nf] = __builtin_amdgcn_mfma_f32_16x16x32_bf16(af, bf, acc[nf], 0, 0, 0);
        }
    }
#pragma unroll
    for (int nf = 0; nf < 2; ++nf) {
        int col = w * 32 + nf * 16 + l15;
#pragma unroll
        for (int j = 0; j < 4; ++j) {
            int row = l4 * 4 + j;
            H1[row][col] = acc[nf][j] + h_one[(size_t)(r0 + row) * 256 + col];
        }
    }
    __syncthreads();

    // LN1
    {
        float4 sc = *(const float4*)&ln1_s[lane * 4];
        float4 bi = *(const float4*)&ln1_b[lane * 4];
#pragma unroll
        for (int rr = 0; rr < 2; ++rr) {
            int row = w * 2 + rr;
            float4 v = *(const float4*)&H1[row][lane * 4];
            float su = v.x + v.y + v.z + v.w;
#pragma unroll
            for (int off = 32; off > 0; off >>= 1) su += __shfl_xor(su, off, 64);
            float mu = su * (1.0f / 256.0f);
            float dx = v.x - mu, dy = v.y - mu, dz = v.z - mu, dw = v.w - mu;
            float s2 = dx * dx + dy * dy + dz * dz + dw * dw;
#pragma unroll
            for (int off = 32; off > 0; off >>= 1) s2 += __shfl_xor(s2, off, 64);
            float inv = rsqrtf(s2 * (1.0f / 256.0f) + LN_EPS);
            float4 o;
            o.x = dx * inv * sc.x + bi.x;
            o.y = dy * inv * sc.y + bi.y;
            o.z = dz * inv * sc.z + bi.z;
            o.w = dw * inv * sc.w + bi.w;
            *(float4*)&H1[row][lane * 4] = o;
            short4v ob;
            ob[0] = f2bf(o.x); ob[1] = f2bf(o.y); ob[2] = f2bf(o.z); ob[3] = f2bf(o.w);
            *(short4v*)&L1[row][lane * 4] = ob;
        }
    }
    __syncthreads();

    // GEMM2: h2 = H1 + silu(L1 @ WmlpT + b_mlp)
    f32x4 acc2[2] = {};
    for (int k0 = 0; k0 < 256; k0 += 32) {
        bf16x8 af = *(const bf16x8*)&L1[l15][k0 + l4 * 8];
#pragma unroll
        for (int nf = 0; nf < 2; ++nf) {
            int n = w * 32 + nf * 16 + l15;
            bf16x8 bf = *(const bf16x8*)&WmlpT[(size_t)n * 256 + k0 + l4 * 8];
            acc2[nf] = __builtin_amdgcn_mfma_f32_16x16x32_bf16(af, bf, acc2[nf], 0, 0, 0);
        }
    }
#pragma unroll
    for (int nf = 0; nf < 2; ++nf) {
        int col = w * 32 + nf * 16 + l15;
        float bm = b_mlp[col];
#pragma unroll
        for (int j = 0; j < 4; ++j) {
            int row = l4 * 4 + j;
            float v = acc2[nf][j] + bm;
            float sg = 1.0f / (1.0f + __expf(-v));
            H1[row][col] = H1[row][col] + v * sg;   // same-lane RMW
        }
    }
    __syncthreads();

    // LN2 -> out
    {
        float4 sc = *(const float4*)&ln2_s[lane * 4];
        float4 bi = *(const float4*)&ln2_b[lane * 4];
#pragma unroll
        for (int rr = 0; rr < 2; ++rr) {
            int row = w * 2 + rr;
            float4 v = *(const float4*)&H1[row][lane * 4];
            float su = v.x + v.y + v.z + v.w;
#pragma unroll
            for (int off = 32; off > 0; off >>= 1) su += __shfl_xor(su, off, 64);
            float mu = su * (1.0f / 256.0f);
            float dx = v.x - mu, dy = v.y - mu, dz = v.z - mu, dw = v.w - mu;
            float s2 = dx * dx + dy * dy + dz * dz + dw * dw;
#pragma unroll
            for (int off = 32; off > 0; off >>= 1) s2 += __shfl_xor(s2, off, 64);
            float inv = rsqrtf(s2 * (1.0f / 256.0f) + LN_EPS);
            float4 o;
            o.x = dx * inv * sc.x + bi.x;
            o.y = dy * inv * sc.y + bi.y;
            o.z = dz * inv * sc.z + bi.z;
            o.w = dw * inv * sc.w + bi.w;
            *(float4*)&out[(size_t)(r0 + row) * 256 + lane * 4] = o;
        }
    }
}

// ---------------------------------------------------------------------------
extern "C" void kernel_launch(void* const* d_in, const int* in_sizes, int n_in,
                              void* d_out, int out_size, void* d_ws, size_t ws_size,
                              hipStream_t stream)
{
    const float* h_one = (const float*)d_in[0];
    const float* W_qkv = (const float*)d_in[1];
    const float* W_out = (const float*)d_in[2];
    const float* ln1_s = (const float*)d_in[3];
    const float* ln1_b = (const float*)d_in[4];
    const float* W_mlp = (const float*)d_in[5];
    const float* b_mlp = (const float*)d_in[6];
    const float* ln2_s = (const float*)d_in[7];
    const float* ln2_b = (const float*)d_in[8];
    float* out = (float*)d_out;

    char* ws = (char*)d_ws;
    short* attn_bf = (short*)ws;                 // 4096*256 bf16 = 2MB
    short* WoutT   = (short*)(ws + 2097152);     // 256*256 bf16 = 128KB
    short* WmlpT   = WoutT + 256 * 256;

    k1_qkv_attn<<<512 + 32, 256, 0, stream>>>(h_one, W_qkv, W_out, W_mlp,
                                              attn_bf, WoutT, WmlpT);
    k2_tail<<<NTOT / 16, 512, 0, stream>>>(attn_bf, WoutT, WmlpT, h_one, b_mlp,
                                           ln1_s, ln1_b, ln2_s, ln2_b, out);
}